// Round 12
// baseline (384.633 us; speedup 1.0000x reference)
//
#include <hip/hip_runtime.h>
#include <hip/hip_bf16.h>

typedef __attribute__((ext_vector_type(4))) float  f32x4;
typedef __attribute__((ext_vector_type(8))) short  short8;

#define H_    1024
#define K_    2048   // 2H
#define B_    32
#define S_    1024
#define M_TOT 32768  // B*S

static __device__ __forceinline__ unsigned short f2bf(float f) {
  __hip_bfloat16 h = __float2bfloat16(f);
  return __builtin_bit_cast(unsigned short, h);
}
static __device__ __forceinline__ float bf2f(unsigned short u) {
  unsigned int x = ((unsigned int)u) << 16;
  return __builtin_bit_cast(float, x);
}

// branchless tanh: 1 - 2/(e^{2x}+1); exp2-based, correct at +/-inf, ~1e-6 err
static __device__ __forceinline__ float fast_tanh(float x) {
  float e = __builtin_amdgcn_exp2f(x * 2.88539008177792681f);  // 2*log2(e)
  return 1.0f - 2.0f * __builtin_amdgcn_rcpf(e + 1.0f);
}

static __device__ __forceinline__ void gload_lds16(const void* g, void* l) {
  __builtin_amdgcn_global_load_lds(
      (const __attribute__((address_space(1))) unsigned int*)g,
      (__attribute__((address_space(3))) unsigned int*)l, 16, 0, 0);
}

// ---------------- prep: We [K][H] fp32 -> WeT [H][K] bf16 ----------------
__global__ void we_transpose_kernel(const float* __restrict__ We,
                                    unsigned short* __restrict__ WeT) {
  __shared__ float tile[32][33];
  int k0 = blockIdx.x * 32;
  int n0 = blockIdx.y * 32;
  int tx = threadIdx.x, ty = threadIdx.y;  // block (32,8)
#pragma unroll
  for (int i = 0; i < 32; i += 8)
    tile[ty + i][tx] = We[(size_t)(k0 + ty + i) * H_ + n0 + tx];
  __syncthreads();
#pragma unroll
  for (int i = 0; i < 32; i += 8)
    WeT[(size_t)(n0 + ty + i) * K_ + k0 + tx] = f2bf(tile[tx][ty + i]);
}

// ---------------- gamma_dec[b][h] = bd[h] + dec[b,:] @ Wd[:,h] ----------------
__global__ void gdec_kernel(const float* __restrict__ dec,
                            const float* __restrict__ Wd,
                            const float* __restrict__ bd,
                            float* __restrict__ gdec) {
  int h = blockIdx.x * 256 + threadIdx.x;
  int b = blockIdx.y;
  const float* dp = dec + b * H_;
  float acc = bd[h];
#pragma unroll 8
  for (int k = 0; k < H_; ++k) acc += dp[k] * Wd[(size_t)k * H_ + h];
  gdec[b * H_ + h] = acc;
}

// ---------------- fused CONVERT + GEMM + tanh + Wv-reduce ------------------
// 256x256 tile, 8 waves (2M x 4N), per-wave 128x64. R8 skeleton (proven):
// whole-tile 2-buffer, reads-upfront COMPUTE, 128-B LDS rows with the
// R3/R4-verified 0-conflict swizzle (slot = chunk ^ (row&7)), setprio.
// R12: A is reg-staged fp32 DIRECTLY from ctx (convert kernel deleted):
//   ALOAD (8x f32x4, issued first) ; BSTAGE (4 gload_lds, younger in FIFO) ;
//   AWRITE (cvt + swizzled ds_write_b128; lifetime ends BEFORE COMPUTE --
//   R9's spill came from holding a[] across the MFMA cluster).
// Each block also stores bf16 A for its nt-owned k-quarter (tn>>3 == nt)
// to Abf -- balanced 256 KB/block -- which ct_partial consumes.
// grid: 512 blocks, XCD-swizzled: bid&7 = XCD owns 16 m-tiles (n fastest).
__global__ __launch_bounds__(512)
void gemm_score_kernel(const float* __restrict__ ctx,
                       const unsigned short* __restrict__ WeT,
                       const float* __restrict__ be,
                       const float* __restrict__ gdec,
                       const float* __restrict__ Wv,
                       float* __restrict__ spart_g,
                       unsigned short* __restrict__ Abf) {
  __shared__ __align__(16) unsigned short As[2][256 * 64];  // 2 x 32 KB
  __shared__ __align__(16) unsigned short Bs[2][256 * 64];  // 2 x 32 KB
  __shared__ float bg[256];
  __shared__ float wvl[256];
  __shared__ float sred[4][256];

  const int tid  = threadIdx.x;
  const int lane = tid & 63;
  const int wid  = tid >> 6;          // 0..7
  const int wr   = wid >> 2;          // 0..1  (M)
  const int wc   = wid & 3;           // 0..3  (N)
  const int lc = lane & 15, l4 = lane >> 4;

  // XCD-aware decode: bid%8 = XCD; XCD x gets m-tiles [x*16, x*16+16), n fastest
  const int bid = blockIdx.x;
  const int x   = bid & 7;
  const int c   = bid >> 3;           // 0..63
  const int mt  = x * 16 + (c >> 2);  // 0..127
  const int nt  = c & 3;              // 0..3
  const int m0  = mt * 256;
  const int n0  = nt * 256;
  const int b   = m0 >> 10;           // S=1024, 256|S so one b per block

  if (tid < 256) {
    bg[tid]  = be[n0 + tid] + gdec[b * H_ + n0 + tid];
    wvl[tid] = Wv[n0 + tid];
  }

  // ---- A reg-staging: thread t -> row t>>1 (0..255), k-half t&1 (32 floats)
  const int arow = tid >> 1;
  const int akh  = tid & 1;
  const int arx  = arow & 7;          // swizzle key (matches read's lc&7)
  const float*    aF   = ctx + (size_t)(m0 + arow) * K_ + akh * 32;
  unsigned short* aStG = Abf + (size_t)(m0 + arow) * K_ + akh * 32;
  char* aL[2] = {(char*)&As[0][arow * 64], (char*)&As[1][arow * 64]};

  // ---- B staging via global_load_lds: issue g rows g*64 + wid*8 + (l>>3),
  // chunk l&7; LDS dest linear; source chunk pre-swizzled by row&7 = l>>3.
  const int g8  = lane >> 3;
  const int csw = ((lane & 7) ^ g8) * 8;
  const unsigned short* bB = WeT + (size_t)(n0 + wid * 8 + g8) * K_ + csw;

  // fragment read byte-offsets (thread-constant)
  int aoff[2][8], boff[2][4];
#pragma unroll
  for (int ks = 0; ks < 2; ++ks) {
#pragma unroll
    for (int mh = 0; mh < 2; ++mh)
#pragma unroll
      for (int mi = 0; mi < 4; ++mi) {
        int r = wr * 128 + mh * 64 + mi * 16 + lc;
        aoff[ks][mh * 4 + mi] = r * 128 + ((((ks << 2) | l4) ^ (lc & 7)) << 4);
      }
#pragma unroll
    for (int ni = 0; ni < 4; ++ni) {
      int r = wc * 64 + ni * 16 + lc;
      boff[ks][ni] = r * 128 + ((((ks << 2) | l4) ^ (lc & 7)) << 4);
    }
  }

  f32x4 acc[8][4];
#pragma unroll
  for (int mi = 0; mi < 8; ++mi)
#pragma unroll
    for (int ni = 0; ni < 4; ++ni) {
      f32x4 z = {0.f, 0.f, 0.f, 0.f};
      acc[mi][ni] = z;
    }

  f32x4 a[8];
  auto ALOAD = [&](int tn) {
#pragma unroll
    for (int j = 0; j < 8; ++j)
      a[j] = *(const f32x4*)(aF + tn * 64 + j * 4);
  };
  auto AWRITE = [&](char* aLb, int tn) {
    const bool own = (tn >> 3) == nt;   // block-uniform
#pragma unroll
    for (int cc = 0; cc < 4; ++cc) {
      short8 v;
      v[0] = (short)f2bf(a[2 * cc][0]);
      v[1] = (short)f2bf(a[2 * cc][1]);
      v[2] = (short)f2bf(a[2 * cc][2]);
      v[3] = (short)f2bf(a[2 * cc][3]);
      v[4] = (short)f2bf(a[2 * cc + 1][0]);
      v[5] = (short)f2bf(a[2 * cc + 1][1]);
      v[6] = (short)f2bf(a[2 * cc + 1][2]);
      v[7] = (short)f2bf(a[2 * cc + 1][3]);
      *(short8*)(aLb + (((akh * 4 + cc) ^ arx) << 4)) = v;
      if (own) *(short8*)(aStG + (size_t)tn * 64 + cc * 8) = v;
    }
  };
  auto BSTAGE = [&](int bi, int tn) {
    const int ko = tn * 64;
#pragma unroll
    for (int g = 0; g < 4; ++g)
      gload_lds16(bB + (size_t)g * 64 * K_ + ko, &Bs[bi][(g * 64 + wid * 8) * 64]);
  };
  auto COMPUTE = [&](int bi) {
#pragma unroll
    for (int ks = 0; ks < 2; ++ks) {
      short8 bfr[4], afr[8];
#pragma unroll
      for (int ni = 0; ni < 4; ++ni)
        bfr[ni] = *(const short8*)((const char*)&Bs[bi][0] + boff[ks][ni]);
#pragma unroll
      for (int f = 0; f < 8; ++f)
        afr[f] = *(const short8*)((const char*)&As[bi][0] + aoff[ks][f]);
      __builtin_amdgcn_s_setprio(1);
#pragma unroll
      for (int mh = 0; mh < 2; ++mh)
#pragma unroll
        for (int mi = 0; mi < 4; ++mi)
#pragma unroll
          for (int ni = 0; ni < 4; ++ni)
            acc[mh * 4 + mi][ni] = __builtin_amdgcn_mfma_f32_16x16x32_bf16(
                afr[mh * 4 + mi], bfr[ni], acc[mh * 4 + mi][ni], 0, 0, 0);
      __builtin_amdgcn_s_setprio(0);
    }
  };

  // prologue: stage tile 0
  ALOAD(0);
  BSTAGE(0, 0);
  AWRITE(aL[0], 0);
  asm volatile("s_waitcnt vmcnt(0) lgkmcnt(0)" ::: "memory");
  __builtin_amdgcn_s_barrier();
  __builtin_amdgcn_sched_barrier(0);

#pragma unroll 2
  for (int kt = 0; kt < 32; ++kt) {
    const int cur = kt & 1;
    if (kt < 31) {
      ALOAD(kt + 1);               // fp32 loads issued first (oldest in FIFO)
      BSTAGE(cur ^ 1, kt + 1);     // B DMA flies under the A cvt/write
      AWRITE(aL[cur ^ 1], kt + 1); // cvt+ds_write (+owned global store);
                                   // a[] lifetime ends here (no spill)
    }
    COMPUTE(cur);
    asm volatile("s_waitcnt vmcnt(0) lgkmcnt(0)" ::: "memory");
    __builtin_amdgcn_s_barrier();
    __builtin_amdgcn_sched_barrier(0);
  }

  // ---- epilogue: g = acc + be + gdec; tanh; * Wv; reduce over 256 cols
#pragma unroll
  for (int ami = 0; ami < 8; ++ami) {
#pragma unroll
    for (int j = 0; j < 4; ++j) {
      float s = 0.f;
#pragma unroll
      for (int ni = 0; ni < 4; ++ni) {
        int cC  = wc * 64 + ni * 16 + lc;
        s += fast_tanh(acc[ami][ni][j] + bg[cC]) * wvl[cC];
      }
#pragma unroll
      for (int off = 1; off < 16; off <<= 1) s += __shfl_xor(s, off);
      if (lc == 0) sred[wc][wr * 128 + ami * 16 + l4 * 4 + j] = s;
    }
  }
  __syncthreads();
  if (tid < 256)
    spart_g[(size_t)nt * M_TOT + m0 + tid] =
        sred[0][tid] + sred[1][tid] + sred[2][tid] + sred[3][tid];
}

// ---------------- reduce partials + bv, softmax over S per b ----------------
__global__ void softmax_kernel(const float* __restrict__ spart,
                               const float* __restrict__ bv,
                               float* __restrict__ wout, int nparts) {
  int b = blockIdx.x, tid = threadIdx.x;  // 256 threads
  int lane = tid & 63, wid = tid >> 6;
  __shared__ float red[4];
  float bv0 = bv[0];
  float v[4];
#pragma unroll
  for (int i = 0; i < 4; ++i) {
    int m = b * S_ + i * 256 + tid;
    float s = bv0;
    for (int nb = 0; nb < nparts; ++nb) s += spart[(size_t)nb * M_TOT + m];
    v[i] = s;
  }
  float mx = fmaxf(fmaxf(v[0], v[1]), fmaxf(v[2], v[3]));
#pragma unroll
  for (int off = 1; off < 64; off <<= 1) mx = fmaxf(mx, __shfl_xor(mx, off));
  if (lane == 0) red[wid] = mx;
  __syncthreads();
  mx = fmaxf(fmaxf(red[0], red[1]), fmaxf(red[2], red[3]));
  __syncthreads();
  float e[4], sum = 0.f;
#pragma unroll
  for (int i = 0; i < 4; ++i) {
    e[i] = expf(v[i] - mx);
    sum += e[i];
  }
#pragma unroll
  for (int off = 1; off < 64; off <<= 1) sum += __shfl_xor(sum, off);
  if (lane == 0) red[wid] = sum;
  __syncthreads();
  sum = red[0] + red[1] + red[2] + red[3];
  float inv = 1.f / sum;
#pragma unroll
  for (int i = 0; i < 4; ++i)
    wout[b * S_ + i * 256 + tid] = e[i] * inv;
}

// ---------------- c_t partials from bf16 ctx: grid (32 b, 32 sc) ----------
__global__ __launch_bounds__(256)
void ct_partial_bf_kernel(const unsigned short* __restrict__ ctxb,
                          const float* __restrict__ w,
                          float* __restrict__ part) {
  int tid = threadIdx.x;
  int b = blockIdx.x, sc = blockIdx.y;
  int e0 = tid * 8;
  const float* wp = w + b * S_ + sc * 32;
  const unsigned short* cp = ctxb + (size_t)(b * S_ + sc * 32) * K_ + e0;
  float acc[8];
#pragma unroll
  for (int j = 0; j < 8; ++j) acc[j] = 0.f;
#pragma unroll 4
  for (int s = 0; s < 32; ++s) {
    float ws_ = wp[s];
    short8 v = *(const short8*)(cp + (size_t)s * K_);
#pragma unroll
    for (int j = 0; j < 8; ++j)
      acc[j] += ws_ * bf2f((unsigned short)v[j]);
  }
  float* dst = part + (size_t)sc * 65536 + (size_t)b * K_ + e0;
#pragma unroll
  for (int j = 0; j < 8; ++j) dst[j] = acc[j];
}

__global__ void ct_combine32_kernel(const float* __restrict__ part,
                                    float* __restrict__ out) {
  int idx = blockIdx.x * 256 + threadIdx.x;  // 65536
  float s = 0.f;
#pragma unroll
  for (int p = 0; p < 32; ++p) s += part[(size_t)p * 65536 + idx];
  out[idx] = s;
}

extern "C" void kernel_launch(void* const* d_in, const int* in_sizes, int n_in,
                              void* d_out, int out_size, void* d_ws, size_t ws_size,
                              hipStream_t stream) {
  const float* ctx = (const float*)d_in[0];
  const float* dec = (const float*)d_in[1];
  const float* We  = (const float*)d_in[2];
  const float* be  = (const float*)d_in[3];
  const float* Wd  = (const float*)d_in[4];
  const float* bd  = (const float*)d_in[5];
  const float* Wv  = (const float*)d_in[6];
  const float* bv  = (const float*)d_in[7];
  float* out = (float*)d_out;
  char*  ws  = (char*)d_ws;

  const size_t SZ_ABF  = (size_t)M_TOT * K_ * 2;      // 128 MB
  const size_t OFF_WET = SZ_ABF;                      // 4 MB
  const size_t OFF_GD  = OFF_WET + (size_t)H_ * K_ * 2;
  const size_t OFF_SP  = OFF_GD + (size_t)B_ * H_ * 4;
  const size_t OFF_CT  = OFF_SP + (size_t)8 * M_TOT * 4;

  unsigned short* Abf  = (unsigned short*)ws;
  unsigned short* WeT  = (unsigned short*)(ws + OFF_WET);
  float*          gdec = (float*)(ws + OFF_GD);
  float*          spart= (float*)(ws + OFF_SP);
  float*          ctpt = (float*)(ws + OFF_CT);

  we_transpose_kernel<<<dim3(K_ / 32, H_ / 32), dim3(32, 8), 0, stream>>>(We, WeT);
  gdec_kernel<<<dim3(H_ / 256, B_), 256, 0, stream>>>(dec, Wd, bd, gdec);
  gemm_score_kernel<<<512, 512, 0, stream>>>(ctx, WeT, be, gdec, Wv, spart, Abf);
  softmax_kernel<<<B_, 256, 0, stream>>>(spart, bv, out + 65536, 4);
  ct_partial_bf_kernel<<<dim3(B_, 32), 256, 0, stream>>>(Abf, out + 65536, ctpt);
  ct_combine32_kernel<<<256, 256, 0, stream>>>(ctpt, out);
}

// Round 13
// 350.626 us; speedup vs baseline: 1.0970x; 1.0970x over previous
//
#include <hip/hip_runtime.h>
#include <hip/hip_bf16.h>

typedef __attribute__((ext_vector_type(4))) float  f32x4;
typedef __attribute__((ext_vector_type(8))) short  short8;

#define H_    1024
#define K_    2048   // 2H
#define B_    32
#define S_    1024
#define M_TOT 32768  // B*S

static __device__ __forceinline__ unsigned short f2bf(float f) {
  __hip_bfloat16 h = __float2bfloat16(f);
  return __builtin_bit_cast(unsigned short, h);
}
static __device__ __forceinline__ float bf2f(unsigned short u) {
  unsigned int x = ((unsigned int)u) << 16;
  return __builtin_bit_cast(float, x);
}

// branchless tanh: 1 - 2/(e^{2x}+1); exp2-based, correct at +/-inf, ~1e-6 err
static __device__ __forceinline__ float fast_tanh(float x) {
  float e = __builtin_amdgcn_exp2f(x * 2.88539008177792681f);  // 2*log2(e)
  return 1.0f - 2.0f * __builtin_amdgcn_rcpf(e + 1.0f);
}

static __device__ __forceinline__ void gload_lds16(const void* g, void* l) {
  __builtin_amdgcn_global_load_lds(
      (const __attribute__((address_space(1))) unsigned int*)g,
      (__attribute__((address_space(3))) unsigned int*)l, 16, 0, 0);
}

// ---------------- prep: ctx fp32 [M][K] -> bf16 [M][K] ----------------
__global__ __launch_bounds__(256)
void ctx_convert_kernel(const float* __restrict__ ctx,
                        unsigned short* __restrict__ ctxb) {
  int idx = blockIdx.x * 256 + threadIdx.x;  // 524288 threads
#pragma unroll
  for (int j = 0; j < 16; ++j) {
    size_t e = ((size_t)j * 524288 + idx) * 8;
    f32x4 a = *(const f32x4*)(ctx + e);
    f32x4 b = *(const f32x4*)(ctx + e + 4);
    short8 v;
    v[0] = (short)f2bf(a[0]); v[1] = (short)f2bf(a[1]);
    v[2] = (short)f2bf(a[2]); v[3] = (short)f2bf(a[3]);
    v[4] = (short)f2bf(b[0]); v[5] = (short)f2bf(b[1]);
    v[6] = (short)f2bf(b[2]); v[7] = (short)f2bf(b[3]);
    *(short8*)(ctxb + e) = v;
  }
}

// ---------------- prep: We [K][H] fp32 -> WeT [H][K] bf16 ----------------
__global__ void we_transpose_kernel(const float* __restrict__ We,
                                    unsigned short* __restrict__ WeT) {
  __shared__ float tile[32][33];
  int k0 = blockIdx.x * 32;
  int n0 = blockIdx.y * 32;
  int tx = threadIdx.x, ty = threadIdx.y;  // block (32,8)
#pragma unroll
  for (int i = 0; i < 32; i += 8)
    tile[ty + i][tx] = We[(size_t)(k0 + ty + i) * H_ + n0 + tx];
  __syncthreads();
#pragma unroll
  for (int i = 0; i < 32; i += 8)
    WeT[(size_t)(n0 + ty + i) * K_ + k0 + tx] = f2bf(tile[tx][ty + i]);
}

// ---------------- gamma_dec[b][h] = bd[h] + dec[b,:] @ Wd[:,h] ----------------
__global__ void gdec_kernel(const float* __restrict__ dec,
                            const float* __restrict__ Wd,
                            const float* __restrict__ bd,
                            float* __restrict__ gdec) {
  int h = blockIdx.x * 256 + threadIdx.x;
  int b = blockIdx.y;
  const float* dp = dec + b * H_;
  float acc = bd[h];
#pragma unroll 8
  for (int k = 0; k < H_; ++k) acc += dp[k] * Wd[(size_t)k * H_ + h];
  gdec[b * H_ + h] = acc;
}

// ---------------- fused GEMM + tanh + Wv-reduce -> partial scores ----------
// 256x256 tile, 8 waves (2M x 4N), per-wave 128x64.
// R13: B BYPASSES LDS -- fragments loaded per-wave straight from L2
// (WeT = 4 MB, L2-resident; frag addr = WeT[(n0+wc*64+ni*16+lc)*K + k]).
// LDS holds A only (2 x 32 KB dbuf): traffic/tile drops 256->160 KB.
// Counted-vmcnt falls out naturally: per iter the FIFO is
//   [A-DMA(4) ; Bks1(4) ; Bks0'(4)] -- the compiler's wait on Bks1 before
//   the ks1 MFMAs retires A too, so the end-of-iter vmcnt(4) keeps the
//   next-tile ks0 B-loads in flight (T4: never 0 in the main loop).
// Register WAR on bfr0 is safe: the reload is issued after the MFMAs that
// read it (in-order issue; MFMA reads regs at issue).
// A path unchanged from champion: gload_lds linear dest + pre-XOR source,
// reads XOR'd with the same involution (R3/R4-measured 0 conflicts).
// grid: 512 blocks, XCD-swizzled: bid&7 = XCD owns 16 m-tiles (n fastest).
__global__ __launch_bounds__(512)
void gemm_score_kernel(const unsigned short* __restrict__ Abf,
                       const unsigned short* __restrict__ WeT,
                       const float* __restrict__ be,
                       const float* __restrict__ gdec,
                       const float* __restrict__ Wv,
                       float* __restrict__ spart_g) {
  __shared__ __align__(16) unsigned short As[2][256 * 64];  // 2 x 32 KB
  __shared__ float bg[256];
  __shared__ float wvl[256];
  __shared__ float sred[4][256];

  const int tid  = threadIdx.x;
  const int lane = tid & 63;
  const int wid  = tid >> 6;          // 0..7
  const int wr   = wid >> 2;          // 0..1  (M)
  const int wc   = wid & 3;           // 0..3  (N)
  const int lc = lane & 15, l4 = lane >> 4;

  // XCD-aware decode: bid%8 = XCD; XCD x gets m-tiles [x*16, x*16+16), n fastest
  const int bid = blockIdx.x;
  const int x   = bid & 7;
  const int c   = bid >> 3;           // 0..63
  const int mt  = x * 16 + (c >> 2);  // 0..127
  const int nt  = c & 3;              // 0..3
  const int m0  = mt * 256;
  const int n0  = nt * 256;
  const int b   = m0 >> 10;           // S=1024, 256|S so one b per block

  if (tid < 256) {
    bg[tid]  = be[n0 + tid] + gdec[b * H_ + n0 + tid];
    wvl[tid] = Wv[n0 + tid];
  }

  // ---- A staging via global_load_lds: issue g rows g*64 + wid*8 + (l>>3),
  // chunk l&7; LDS dest linear; source chunk pre-swizzled by row&7 = l>>3.
  const int g8  = lane >> 3;
  const int csw = ((lane & 7) ^ g8) * 8;
  const unsigned short* aB = Abf + (size_t)(m0 + wid * 8 + g8) * K_ + csw;

  // ---- B direct-from-L2 fragment base: row = n0 + wc*64 + ni*16 + lc
  const unsigned short* bD = WeT + (size_t)(n0 + wc * 64 + lc) * K_ + l4 * 8;

  // A fragment read byte-offsets (thread-constant)
  int aoff[2][8];
#pragma unroll
  for (int ks = 0; ks < 2; ++ks)
#pragma unroll
    for (int mh = 0; mh < 2; ++mh)
#pragma unroll
      for (int mi = 0; mi < 4; ++mi) {
        int r = wr * 128 + mh * 64 + mi * 16 + lc;
        aoff[ks][mh * 4 + mi] = r * 128 + ((((ks << 2) | l4) ^ (lc & 7)) << 4);
      }

  f32x4 acc[8][4];
#pragma unroll
  for (int mi = 0; mi < 8; ++mi)
#pragma unroll
    for (int ni = 0; ni < 4; ++ni) {
      f32x4 z = {0.f, 0.f, 0.f, 0.f};
      acc[mi][ni] = z;
    }

  short8 bfr0[4], bfr1[4];

  auto ASTAGE = [&](int bi, int tn) {
    const int ko = tn * 64;
#pragma unroll
    for (int g = 0; g < 4; ++g)
      gload_lds16(aB + (size_t)g * 64 * K_ + ko, &As[bi][(g * 64 + wid * 8) * 64]);
  };
  auto BLOAD = [&](short8* dst, int tn, int ks) {
#pragma unroll
    for (int ni = 0; ni < 4; ++ni)
      dst[ni] = *(const short8*)(bD + (size_t)ni * 16 * K_ + tn * 64 + ks * 32);
  };
  auto COMPUTE_KS = [&](int bi, int ks, const short8* bfr) {
#pragma unroll
    for (int mh = 0; mh < 2; ++mh) {
      short8 afr[4];
#pragma unroll
      for (int mi = 0; mi < 4; ++mi)
        afr[mi] = *(const short8*)((const char*)&As[bi][0] + aoff[ks][mh * 4 + mi]);
      __builtin_amdgcn_s_setprio(1);
#pragma unroll
      for (int mi = 0; mi < 4; ++mi)
#pragma unroll
        for (int ni = 0; ni < 4; ++ni)
          acc[mh * 4 + mi][ni] = __builtin_amdgcn_mfma_f32_16x16x32_bf16(
              afr[mi], bfr[ni], acc[mh * 4 + mi][ni], 0, 0, 0);
      __builtin_amdgcn_s_setprio(0);
    }
  };

  // prologue: A tile 0 into LDS; first B ks0 frags into regs
  ASTAGE(0, 0);
  BLOAD(bfr0, 0, 0);
  asm volatile("s_waitcnt vmcnt(0)" ::: "memory");  // A(0) in LDS (bfr0 too)
  __builtin_amdgcn_s_barrier();
  __builtin_amdgcn_sched_barrier(0);

#pragma unroll 2
  for (int kt = 0; kt < 32; ++kt) {
    const int cur = kt & 1;
    if (kt < 31) ASTAGE(cur ^ 1, kt + 1);  // A DMA: oldest in FIFO
    BLOAD(bfr1, kt, 1);                    // B ks1 frags
    COMPUTE_KS(cur, 0, bfr0);              // uses bfr0 (already waited)
    if (kt < 31) BLOAD(bfr0, kt + 1, 0);   // next tile's ks0 frags
    COMPUTE_KS(cur, 1, bfr1);              // compiler waits bfr1 -> retires A
    if (kt < 31) {
      asm volatile("s_waitcnt vmcnt(4)" ::: "memory");  // keep bfr0' in flight
    } else {
      asm volatile("s_waitcnt vmcnt(0)" ::: "memory");
    }
    __builtin_amdgcn_s_barrier();
    __builtin_amdgcn_sched_barrier(0);
  }

  // ---- epilogue: g = acc + be + gdec; tanh; * Wv; reduce over 256 cols
#pragma unroll
  for (int ami = 0; ami < 8; ++ami) {
#pragma unroll
    for (int j = 0; j < 4; ++j) {
      float s = 0.f;
#pragma unroll
      for (int ni = 0; ni < 4; ++ni) {
        int cC  = wc * 64 + ni * 16 + lc;
        s += fast_tanh(acc[ami][ni][j] + bg[cC]) * wvl[cC];
      }
#pragma unroll
      for (int off = 1; off < 16; off <<= 1) s += __shfl_xor(s, off);
      if (lc == 0) sred[wc][wr * 128 + ami * 16 + l4 * 4 + j] = s;
    }
  }
  __syncthreads();
  if (tid < 256)
    spart_g[(size_t)nt * M_TOT + m0 + tid] =
        sred[0][tid] + sred[1][tid] + sred[2][tid] + sred[3][tid];
}

// ---------------- reduce partials + bv, softmax over S per b ----------------
__global__ void softmax_kernel(const float* __restrict__ spart,
                               const float* __restrict__ bv,
                               float* __restrict__ wout, int nparts) {
  int b = blockIdx.x, tid = threadIdx.x;  // 256 threads
  int lane = tid & 63, wid = tid >> 6;
  __shared__ float red[4];
  float bv0 = bv[0];
  float v[4];
#pragma unroll
  for (int i = 0; i < 4; ++i) {
    int m = b * S_ + i * 256 + tid;
    float s = bv0;
    for (int nb = 0; nb < nparts; ++nb) s += spart[(size_t)nb * M_TOT + m];
    v[i] = s;
  }
  float mx = fmaxf(fmaxf(v[0], v[1]), fmaxf(v[2], v[3]));
#pragma unroll
  for (int off = 1; off < 64; off <<= 1) mx = fmaxf(mx, __shfl_xor(mx, off));
  if (lane == 0) red[wid] = mx;
  __syncthreads();
  mx = fmaxf(fmaxf(red[0], red[1]), fmaxf(red[2], red[3]));
  __syncthreads();
  float e[4], sum = 0.f;
#pragma unroll
  for (int i = 0; i < 4; ++i) {
    e[i] = expf(v[i] - mx);
    sum += e[i];
  }
#pragma unroll
  for (int off = 1; off < 64; off <<= 1) sum += __shfl_xor(sum, off);
  if (lane == 0) red[wid] = sum;
  __syncthreads();
  sum = red[0] + red[1] + red[2] + red[3];
  float inv = 1.f / sum;
#pragma unroll
  for (int i = 0; i < 4; ++i)
    wout[b * S_ + i * 256 + tid] = e[i] * inv;
}

// ---------------- c_t partials from bf16 ctx: grid (32 b, 32 sc) ----------
__global__ __launch_bounds__(256)
void ct_partial_bf_kernel(const unsigned short* __restrict__ ctxb,
                          const float* __restrict__ w,
                          float* __restrict__ part) {
  int tid = threadIdx.x;
  int b = blockIdx.x, sc = blockIdx.y;
  int e0 = tid * 8;
  const float* wp = w + b * S_ + sc * 32;
  const unsigned short* cp = ctxb + (size_t)(b * S_ + sc * 32) * K_ + e0;
  float acc[8];
#pragma unroll
  for (int j = 0; j < 8; ++j) acc[j] = 0.f;
#pragma unroll 4
  for (int s = 0; s < 32; ++s) {
    float ws_ = wp[s];
    short8 v = *(const short8*)(cp + (size_t)s * K_);
#pragma unroll
    for (int j = 0; j < 8; ++j)
      acc[j] += ws_ * bf2f((unsigned short)v[j]);
  }
  float* dst = part + (size_t)sc * 65536 + (size_t)b * K_ + e0;
#pragma unroll
  for (int j = 0; j < 8; ++j) dst[j] = acc[j];
}

__global__ void ct_combine32_kernel(const float* __restrict__ part,
                                    float* __restrict__ out) {
  int idx = blockIdx.x * 256 + threadIdx.x;  // 65536
  float s = 0.f;
#pragma unroll
  for (int p = 0; p < 32; ++p) s += part[(size_t)p * 65536 + idx];
  out[idx] = s;
}

extern "C" void kernel_launch(void* const* d_in, const int* in_sizes, int n_in,
                              void* d_out, int out_size, void* d_ws, size_t ws_size,
                              hipStream_t stream) {
  const float* ctx = (const float*)d_in[0];
  const float* dec = (const float*)d_in[1];
  const float* We  = (const float*)d_in[2];
  const float* be  = (const float*)d_in[3];
  const float* Wd  = (const float*)d_in[4];
  const float* bd  = (const float*)d_in[5];
  const float* Wv  = (const float*)d_in[6];
  const float* bv  = (const float*)d_in[7];
  float* out = (float*)d_out;
  char*  ws  = (char*)d_ws;

  const size_t SZ_ABF  = (size_t)M_TOT * K_ * 2;      // 128 MB
  const size_t OFF_WET = SZ_ABF;                      // 4 MB
  const size_t OFF_GD  = OFF_WET + (size_t)H_ * K_ * 2;
  const size_t OFF_SP  = OFF_GD + (size_t)B_ * H_ * 4;
  const size_t OFF_CT  = OFF_SP + (size_t)8 * M_TOT * 4;

  unsigned short* Abf  = (unsigned short*)ws;
  unsigned short* WeT  = (unsigned short*)(ws + OFF_WET);
  float*          gdec = (float*)(ws + OFF_GD);
  float*          spart= (float*)(ws + OFF_SP);
  float*          ctpt = (float*)(ws + OFF_CT);

  ctx_convert_kernel<<<2048, 256, 0, stream>>>(ctx, Abf);
  we_transpose_kernel<<<dim3(K_ / 32, H_ / 32), dim3(32, 8), 0, stream>>>(We, WeT);
  gdec_kernel<<<dim3(H_ / 256, B_), 256, 0, stream>>>(dec, Wd, bd, gdec);
  gemm_score_kernel<<<512, 512, 0, stream>>>(Abf, WeT, be, gdec, Wv, spart);
  softmax_kernel<<<B_, 256, 0, stream>>>(spart, bv, out + 65536, 4);
  ct_partial_bf_kernel<<<dim3(B_, 32), 256, 0, stream>>>(Abf, out + 65536, ctpt);
  ct_combine32_kernel<<<256, 256, 0, stream>>>(ctpt, out);
}

// Round 14
// 297.596 us; speedup vs baseline: 1.2925x; 1.1782x over previous
//
#include <hip/hip_runtime.h>
#include <hip/hip_bf16.h>

typedef __attribute__((ext_vector_type(4))) float  f32x4;
typedef __attribute__((ext_vector_type(8))) short  short8;

#define H_    1024
#define K_    2048   // 2H
#define B_    32
#define S_    1024
#define M_TOT 32768  // B*S

static __device__ __forceinline__ unsigned short f2bf(float f) {
  __hip_bfloat16 h = __float2bfloat16(f);
  return __builtin_bit_cast(unsigned short, h);
}
static __device__ __forceinline__ float bf2f(unsigned short u) {
  unsigned int x = ((unsigned int)u) << 16;
  return __builtin_bit_cast(float, x);
}

// branchless tanh: 1 - 2/(e^{2x}+1); exp2-based, correct at +/-inf, ~1e-6 err
static __device__ __forceinline__ float fast_tanh(float x) {
  float e = __builtin_amdgcn_exp2f(x * 2.88539008177792681f);  // 2*log2(e)
  return 1.0f - 2.0f * __builtin_amdgcn_rcpf(e + 1.0f);
}

static __device__ __forceinline__ void gload_lds16(const void* g, void* l) {
  __builtin_amdgcn_global_load_lds(
      (const __attribute__((address_space(1))) unsigned int*)g,
      (__attribute__((address_space(3))) unsigned int*)l, 16, 0, 0);
}

// ---------------- prep: ctx fp32 [M][K] -> bf16 [M][K] ----------------
// nontemporal: every byte touched exactly once here.
__global__ __launch_bounds__(256)
void ctx_convert_kernel(const float* __restrict__ ctx,
                        unsigned short* __restrict__ ctxb) {
  int idx = blockIdx.x * 256 + threadIdx.x;  // 524288 threads
#pragma unroll
  for (int j = 0; j < 16; ++j) {
    size_t e = ((size_t)j * 524288 + idx) * 8;
    f32x4 a = __builtin_nontemporal_load((const f32x4*)(ctx + e));
    f32x4 b = __builtin_nontemporal_load((const f32x4*)(ctx + e + 4));
    short8 v;
    v[0] = (short)f2bf(a[0]); v[1] = (short)f2bf(a[1]);
    v[2] = (short)f2bf(a[2]); v[3] = (short)f2bf(a[3]);
    v[4] = (short)f2bf(b[0]); v[5] = (short)f2bf(b[1]);
    v[6] = (short)f2bf(b[2]); v[7] = (short)f2bf(b[3]);
    __builtin_nontemporal_store(v, (short8*)(ctxb + e));
  }
}

// ---------------- prep: We [K][H] fp32 -> WeT [H][K] bf16 ----------------
__global__ void we_transpose_kernel(const float* __restrict__ We,
                                    unsigned short* __restrict__ WeT) {
  __shared__ float tile[32][33];
  int k0 = blockIdx.x * 32;
  int n0 = blockIdx.y * 32;
  int tx = threadIdx.x, ty = threadIdx.y;  // block (32,8)
#pragma unroll
  for (int i = 0; i < 32; i += 8)
    tile[ty + i][tx] = We[(size_t)(k0 + ty + i) * H_ + n0 + tx];
  __syncthreads();
#pragma unroll
  for (int i = 0; i < 32; i += 8)
    WeT[(size_t)(n0 + ty + i) * K_ + k0 + tx] = f2bf(tile[tx][ty + i]);
}

// ---------------- gamma_dec[b][h] = bd[h] + dec[b,:] @ Wd[:,h] ----------------
__global__ void gdec_kernel(const float* __restrict__ dec,
                            const float* __restrict__ Wd,
                            const float* __restrict__ bd,
                            float* __restrict__ gdec) {
  int h = blockIdx.x * 256 + threadIdx.x;
  int b = blockIdx.y;
  const float* dp = dec + b * H_;
  float acc = bd[h];
#pragma unroll 8
  for (int k = 0; k < H_; ++k) acc += dp[k] * Wd[(size_t)k * H_ + h];
  gdec[b * H_ + h] = acc;
}

// ---------------- fused GEMM + tanh + Wv-reduce -> partial scores ----------
// CHAMPION STRUCTURE (R10, 309 us total): 256x256 tile, 8 waves (2M x 4N),
// per-wave 128x64. K-split quad-buffer, counted vmcnt(4) (never 0 in loop).
// Sub-tile BK=32; buffers 0..3 (128 KB). Iter j: COMPUTE(buf j%4);
// STAGE(buf (j+2)%4, j+2); vmcnt(4) -> sub-tile j+1 landed, j+2 in flight;
// s_barrier. STAGE writes the buffer consumed at iter j-2 -> no WAR.
// Swizzle: LDS slot (row,c) holds global chunk c^(row&3); gload_lds dest
// linear + source pre-XOR; reads XOR with same involution (R10-verified,
// 0 measured conflicts at this layout).
// grid: 512 blocks, XCD-swizzled: bid&7 = XCD owns 16 m-tiles (n fastest).
__global__ __launch_bounds__(512, 2)
void gemm_score_kernel(const unsigned short* __restrict__ Abf,
                       const unsigned short* __restrict__ WeT,
                       const float* __restrict__ be,
                       const float* __restrict__ gdec,
                       const float* __restrict__ Wv,
                       float* __restrict__ spart_g) {
  __shared__ __align__(16) unsigned short As[4][256 * 32];  // 4 x 16 KB
  __shared__ __align__(16) unsigned short Bs[4][256 * 32];  // 4 x 16 KB
  __shared__ float bg[256];
  __shared__ float wvl[256];
  __shared__ float sred[4][256];

  const int tid  = threadIdx.x;
  const int lane = tid & 63;
  const int wid  = tid >> 6;          // 0..7
  const int wr   = wid >> 2;          // 0..1  (M)
  const int wc   = wid & 3;           // 0..3  (N)
  const int lc = lane & 15, l4 = lane >> 4;

  // XCD-aware decode: bid%8 = XCD; XCD x gets m-tiles [x*16, x*16+16), n fastest
  const int bid = blockIdx.x;
  const int x   = bid & 7;
  const int c   = bid >> 3;           // 0..63
  const int mt  = x * 16 + (c >> 2);  // 0..127
  const int nt  = c & 3;              // 0..3
  const int m0  = mt * 256;
  const int n0  = nt * 256;
  const int b   = m0 >> 10;           // S=1024, 256|S so one b per block

  if (tid < 256) {
    bg[tid]  = be[n0 + tid] + gdec[b * H_ + n0 + tid];
    wvl[tid] = Wv[n0 + tid];
  }

  // staging: per sub-tile, issue i in {0,1}: rows i*128 + wid*16 + (lane>>2),
  // chunk lane&3 (rows are 64 B = 4 x 16B chunks). LDS dest linear;
  // source chunk pre-swizzled by row&3 = (lane>>2)&3.
  const int srow = lane >> 2;                       // 0..15 within wave's 16 rows
  const int csw  = ((lane & 3) ^ (srow & 3)) * 8;   // swizzled source col (elem)
  const unsigned short* aB = Abf + (size_t)(m0 + wid * 16 + srow) * K_ + csw;
  const unsigned short* bB = WeT + (size_t)(n0 + wid * 16 + srow) * K_ + csw;

  f32x4 acc[8][4];
#pragma unroll
  for (int mi = 0; mi < 8; ++mi)
#pragma unroll
    for (int ni = 0; ni < 4; ++ni) {
      f32x4 z = {0.f, 0.f, 0.f, 0.f};
      acc[mi][ni] = z;
    }

  auto STAGE = [&](int bi, int j) {
    const int ko = j * 32;
#pragma unroll
    for (int i = 0; i < 2; ++i) {
      gload_lds16(aB + (size_t)i * 128 * K_ + ko,
                  &As[bi][(i * 128 + wid * 16) * 32]);
      gload_lds16(bB + (size_t)i * 128 * K_ + ko,
                  &Bs[bi][(i * 128 + wid * 16) * 32]);
    }
  };
  auto COMPUTE = [&](int bi) {
    short8 bfr[4];
#pragma unroll
    for (int ni = 0; ni < 4; ++ni) {
      int r = wc * 64 + ni * 16 + lc;
      bfr[ni] = *(const short8*)((const char*)&Bs[bi][0] + r * 64 +
                                 ((l4 ^ (lc & 3)) << 4));
    }
#pragma unroll
    for (int mh = 0; mh < 2; ++mh) {
      short8 afr[4];
#pragma unroll
      for (int mi = 0; mi < 4; ++mi) {
        int r = wr * 128 + mh * 64 + mi * 16 + lc;
        afr[mi] = *(const short8*)((const char*)&As[bi][0] + r * 64 +
                                   ((l4 ^ (lc & 3)) << 4));
      }
      __builtin_amdgcn_s_setprio(1);
#pragma unroll
      for (int mi = 0; mi < 4; ++mi)
#pragma unroll
        for (int ni = 0; ni < 4; ++ni)
          acc[mh * 4 + mi][ni] = __builtin_amdgcn_mfma_f32_16x16x32_bf16(
              afr[mi], bfr[ni], acc[mh * 4 + mi][ni], 0, 0, 0);
      __builtin_amdgcn_s_setprio(0);
    }
  };

#define GS_ITER(j, bi)                                    \
  do {                                                    \
    COMPUTE(bi);                                          \
    STAGE(((bi) + 2) & 3, (j) + 2);                       \
    asm volatile("s_waitcnt vmcnt(4)" ::: "memory");      \
    __builtin_amdgcn_s_barrier();                         \
    __builtin_amdgcn_sched_barrier(0);                    \
  } while (0)

  // prologue: 2-deep prefetch (sub-tiles 0,1 -> 8 outstanding/wave)
  STAGE(0, 0);
  STAGE(1, 1);
  asm volatile("s_waitcnt vmcnt(4) lgkmcnt(0)" ::: "memory");  // sub 0 landed
  __builtin_amdgcn_s_barrier();
  __builtin_amdgcn_sched_barrier(0);

  for (int jj = 0; jj < 60; jj += 4) {  // j = 0..59, static buffer indices
    GS_ITER(jj + 0, 0);
    GS_ITER(jj + 1, 1);
    GS_ITER(jj + 2, 2);
    GS_ITER(jj + 3, 3);
  }
  GS_ITER(60, 0);   // stages sub 62
  GS_ITER(61, 1);   // stages sub 63
  // j=62: sub 62 in buf2 (landed at j=61's vmcnt(4)); sub 63 still in flight
  COMPUTE(2);
  asm volatile("s_waitcnt vmcnt(0)" ::: "memory");
  __builtin_amdgcn_s_barrier();
  __builtin_amdgcn_sched_barrier(0);
  // j=63
  COMPUTE(3);
#undef GS_ITER

  // ---- epilogue: g = acc + be + gdec; tanh; * Wv; reduce over 256 cols
#pragma unroll
  for (int ami = 0; ami < 8; ++ami) {
#pragma unroll
    for (int j = 0; j < 4; ++j) {
      float s = 0.f;
#pragma unroll
      for (int ni = 0; ni < 4; ++ni) {
        int cC  = wc * 64 + ni * 16 + lc;
        s += fast_tanh(acc[ami][ni][j] + bg[cC]) * wvl[cC];
      }
#pragma unroll
      for (int off = 1; off < 16; off <<= 1) s += __shfl_xor(s, off);
      if (lc == 0) sred[wc][wr * 128 + ami * 16 + l4 * 4 + j] = s;
    }
  }
  __syncthreads();
  if (tid < 256)
    spart_g[(size_t)nt * M_TOT + m0 + tid] =
        sred[0][tid] + sred[1][tid] + sred[2][tid] + sred[3][tid];
}

// ---------------- reduce partials + bv, softmax over S per b ----------------
__global__ void softmax_kernel(const float* __restrict__ spart,
                               const float* __restrict__ bv,
                               float* __restrict__ wout, int nparts) {
  int b = blockIdx.x, tid = threadIdx.x;  // 256 threads
  int lane = tid & 63, wid = tid >> 6;
  __shared__ float red[4];
  float bv0 = bv[0];
  float v[4];
#pragma unroll
  for (int i = 0; i < 4; ++i) {
    int m = b * S_ + i * 256 + tid;
    float s = bv0;
    for (int nb = 0; nb < nparts; ++nb) s += spart[(size_t)nb * M_TOT + m];
    v[i] = s;
  }
  float mx = fmaxf(fmaxf(v[0], v[1]), fmaxf(v[2], v[3]));
#pragma unroll
  for (int off = 1; off < 64; off <<= 1) mx = fmaxf(mx, __shfl_xor(mx, off));
  if (lane == 0) red[wid] = mx;
  __syncthreads();
  mx = fmaxf(fmaxf(red[0], red[1]), fmaxf(red[2], red[3]));
  __syncthreads();
  float e[4], sum = 0.f;
#pragma unroll
  for (int i = 0; i < 4; ++i) {
    e[i] = expf(v[i] - mx);
    sum += e[i];
  }
#pragma unroll
  for (int off = 1; off < 64; off <<= 1) sum += __shfl_xor(sum, off);
  if (lane == 0) red[wid] = sum;
  __syncthreads();
  sum = red[0] + red[1] + red[2] + red[3];
  float inv = 1.f / sum;
#pragma unroll
  for (int i = 0; i < 4; ++i)
    wout[b * S_ + i * 256 + tid] = e[i] * inv;
}

// ---------------- c_t partials from bf16 ctx: grid (32 b, 16 sc) ----------
// 64 s-rows per block (split-K 16): halves partial traffic vs 32-way.
__global__ __launch_bounds__(256)
void ct_partial_bf_kernel(const unsigned short* __restrict__ ctxb,
                          const float* __restrict__ w,
                          float* __restrict__ part) {
  int tid = threadIdx.x;
  int b = blockIdx.x, sc = blockIdx.y;
  int e0 = tid * 8;
  const float* wp = w + b * S_ + sc * 64;
  const unsigned short* cp = ctxb + (size_t)(b * S_ + sc * 64) * K_ + e0;
  float acc[8];
#pragma unroll
  for (int j = 0; j < 8; ++j) acc[j] = 0.f;
#pragma unroll 4
  for (int s = 0; s < 64; ++s) {
    float ws_ = wp[s];
    short8 v = __builtin_nontemporal_load((const short8*)(cp + (size_t)s * K_));
#pragma unroll
    for (int j = 0; j < 8; ++j)
      acc[j] += ws_ * bf2f((unsigned short)v[j]);
  }
  float* dst = part + (size_t)sc * 65536 + (size_t)b * K_ + e0;
#pragma unroll
  for (int j = 0; j < 8; ++j) dst[j] = acc[j];
}

__global__ void ct_combine16_kernel(const float* __restrict__ part,
                                    float* __restrict__ out) {
  int idx = blockIdx.x * 256 + threadIdx.x;  // 65536
  float s = 0.f;
#pragma unroll
  for (int p = 0; p < 16; ++p) s += part[(size_t)p * 65536 + idx];
  out[idx] = s;
}

extern "C" void kernel_launch(void* const* d_in, const int* in_sizes, int n_in,
                              void* d_out, int out_size, void* d_ws, size_t ws_size,
                              hipStream_t stream) {
  const float* ctx = (const float*)d_in[0];
  const float* dec = (const float*)d_in[1];
  const float* We  = (const float*)d_in[2];
  const float* be  = (const float*)d_in[3];
  const float* Wd  = (const float*)d_in[4];
  const float* bd  = (const float*)d_in[5];
  const float* Wv  = (const float*)d_in[6];
  const float* bv  = (const float*)d_in[7];
  float* out = (float*)d_out;
  char*  ws  = (char*)d_ws;

  const size_t SZ_ABF  = (size_t)M_TOT * K_ * 2;      // 128 MB
  const size_t OFF_WET = SZ_ABF;                      // 4 MB
  const size_t OFF_GD  = OFF_WET + (size_t)H_ * K_ * 2;
  const size_t OFF_SP  = OFF_GD + (size_t)B_ * H_ * 4;
  const size_t OFF_CT  = OFF_SP + (size_t)8 * M_TOT * 4;

  unsigned short* Abf  = (unsigned short*)ws;
  unsigned short* WeT  = (unsigned short*)(ws + OFF_WET);
  float*          gdec = (float*)(ws + OFF_GD);
  float*          spart= (float*)(ws + OFF_SP);
  float*          ctpt = (float*)(ws + OFF_CT);

  ctx_convert_kernel<<<2048, 256, 0, stream>>>(ctx, Abf);
  we_transpose_kernel<<<dim3(K_ / 32, H_ / 32), dim3(32, 8), 0, stream>>>(We, WeT);
  gdec_kernel<<<dim3(H_ / 256, B_), 256, 0, stream>>>(dec, Wd, bd, gdec);
  gemm_score_kernel<<<512, 512, 0, stream>>>(Abf, WeT, be, gdec, Wv, spart);
  softmax_kernel<<<B_, 256, 0, stream>>>(spart, bv, out + 65536, 4);
  ct_partial_bf_kernel<<<dim3(B_, 16), 256, 0, stream>>>(Abf, out + 65536, ctpt);
  ct_combine16_kernel<<<256, 256, 0, stream>>>(ctpt, out);
}